// Round 1
// 858.730 us; speedup vs baseline: 1.1084x; 1.1084x over previous
//
#include <hip/hip_runtime.h>
#include <stdint.h>

#define D_MODELC 512
#define N_HEADSC 8
#define DKH 64
#define BATCH 16
#define SEQ 1024
#define M_TOT (BATCH*SEQ)    // 16384
#define NBH (BATCH*N_HEADSC) // 128

typedef __attribute__((ext_vector_type(8))) short short8;
typedef __attribute__((ext_vector_type(4))) float float4v;
typedef __attribute__((ext_vector_type(4))) unsigned short ushort4v;

__device__ inline unsigned short f2bf(float f) {
    unsigned u = __float_as_uint(f);
    u += 0x7FFFu + ((u >> 16) & 1u);   // RNE
    return (unsigned short)(u >> 16);
}

__device__ inline void gl2lds16(const void* g, void* l) {
    __builtin_amdgcn_global_load_lds(
        (__attribute__((address_space(1))) void*)g,
        (__attribute__((address_space(3))) void*)l, 16, 0, 0);
}

// ---------------- kernel 0a: x fp32 -> bf16 ----------------
__global__ void k_cvt_x(const float* __restrict__ x, unsigned short* __restrict__ xb) {
    int i = (blockIdx.x * 256 + threadIdx.x) * 4;   // 8192 blocks * 1024 = 8388608 exact
    float4v v = *(const float4v*)(x + i);
    ushort4v o;
    o.x = f2bf(v.x); o.y = f2bf(v.y); o.z = f2bf(v.z); o.w = f2bf(v.w);
    *(ushort4v*)(xb + i) = o;
}

// ---------------- kernel 0b: W (K,N) fp32 -> Wt[n][k] bf16, LDS tile transpose --------
__global__ void k_wt(const float* __restrict__ Wq, const float* __restrict__ Wk,
                     const float* __restrict__ Wv, const float* __restrict__ Wo,
                     unsigned short* __restrict__ Wqkvt, unsigned short* __restrict__ Wot) {
    __shared__ float tile[32][33];
    const int blk = blockIdx.x;            // 1024 = 4 mats * 16 * 16 tiles
    const int mat = blk >> 8;
    const int t2  = blk & 255;
    const int kt = (t2 >> 4) * 32;         // row of W (input dim k)
    const int nt = (t2 & 15) * 32;         // col of W (output dim n)
    const float* W = mat == 0 ? Wq : mat == 1 ? Wk : mat == 2 ? Wv : Wo;
    const int tid = threadIdx.x;
    const int cx = tid & 31, ry = tid >> 5;   // 8 rows per pass
#pragma unroll
    for (int p = 0; p < 4; ++p) {
        int kr = ry + p * 8;
        tile[kr][cx] = W[(size_t)(kt + kr) * 512 + nt + cx];
    }
    __syncthreads();
    unsigned short* DST = (mat < 3) ? (Wqkvt + (size_t)mat * 512 * 512) : Wot;
#pragma unroll
    for (int p = 0; p < 4; ++p) {
        int nr = ry + p * 8;
        DST[(size_t)(nt + nr) * 512 + kt + cx] = f2bf(tile[cx][nr]);
    }
}

// ---------------- GEMM: C = A(bf16 M x512) @ Bt^T + bias ----------------
// MODE 0: A=xb, Bt=Wqkv_t[1536][512]; epilogue scatters Q(scaled)/K/Vt bf16.
// MODE 1: A=ctx, Bt=Wo_t[512][512]; epilogue writes fp32 out + bo.
template<int MODE>
__global__ __launch_bounds__(256, 2) void k_gemm(
    const unsigned short* __restrict__ A,
    const unsigned short* __restrict__ Bt,
    const float* __restrict__ bias0,
    const float* __restrict__ bias1,
    const float* __restrict__ bias2,
    unsigned short* __restrict__ Qb,
    unsigned short* __restrict__ Kb,
    unsigned short* __restrict__ Vtb,
    float* __restrict__ Out)
{
    __shared__ __align__(16) unsigned short As[128 * 32];
    __shared__ __align__(16) unsigned short Bs[128 * 32];
    const int m0 = blockIdx.y * 128;
    const int n0 = blockIdx.x * 128;
    const int tid = threadIdx.x;
    const int w = tid >> 6, l = tid & 63;
    const int lm = l & 15, q4 = l >> 4;
    const int wm = (w >> 1) * 64, wn = (w & 1) * 64;

    float4v acc[4][4] = {};

    for (int k0 = 0; k0 < 512; k0 += 32) {
#pragma unroll
        for (int r = 0; r < 2; ++r) {
            int e = tid * 8 + r * 2048;          // flat bf16 idx into 128x32 tile
            int row = e >> 5, col = e & 31;
            gl2lds16(A  + (size_t)(m0 + row) * 512 + k0 + col,
                     (char*)As + w * 1024 + r * 4096);
            gl2lds16(Bt + (size_t)(n0 + row) * 512 + k0 + col,
                     (char*)Bs + w * 1024 + r * 4096);
        }
        __syncthreads();
        short8 af[4], bfr[4];
#pragma unroll
        for (int mi = 0; mi < 4; ++mi)
            af[mi] = *(const short8*)(As + (wm + mi * 16 + lm) * 32 + q4 * 8);
#pragma unroll
        for (int ni = 0; ni < 4; ++ni)
            bfr[ni] = *(const short8*)(Bs + (wn + ni * 16 + lm) * 32 + q4 * 8);
#pragma unroll
        for (int mi = 0; mi < 4; ++mi)
#pragma unroll
            for (int ni = 0; ni < 4; ++ni)
                acc[mi][ni] = __builtin_amdgcn_mfma_f32_16x16x32_bf16(
                    af[mi], bfr[ni], acc[mi][ni], 0, 0, 0);
        __syncthreads();
    }

#pragma unroll
    for (int mi = 0; mi < 4; ++mi)
#pragma unroll
        for (int ni = 0; ni < 4; ++ni)
#pragma unroll
            for (int r = 0; r < 4; ++r) {
                int m = m0 + wm + mi * 16 + q4 * 4 + r;
                int n = n0 + wn + ni * 16 + lm;
                float v = acc[mi][ni][r];
                if (MODE == 0) {
                    int which = n >> 9;
                    int nn = n & 511;
                    int h = nn >> 6, d = nn & 63;
                    int b = m >> 10, s = m & 1023;
                    size_t qkoff = (((size_t)(b * N_HEADSC + h)) * SEQ + s) * DKH + d;
                    if (which == 0) {
                        v = (v + bias0[nn]) * 0.125f;    // fold 1/sqrt(dk), exact pow2
                        Qb[qkoff] = f2bf(v);
                    } else if (which == 1) {
                        Kb[qkoff] = f2bf(v + bias1[nn]);
                    } else {
                        Vtb[(((size_t)(b * N_HEADSC + h)) * DKH + d) * SEQ + s] =
                            f2bf(v + bias2[nn]);
                    }
                } else {
                    Out[(size_t)m * 512 + n] = v + bias0[n];
                }
            }
}

// ---------------- kernel 2: scores + softmax + attn write + PV (fused) ----------------
// one block = 32 query rows of one (b,h); phase A/B/C: wave w owns key cols
// [w*256, w*256+256). phase D (PV): wave w owns output rows rt*16..rt*16+16
// (rt=w&1) and d columns dt*32..dt*32+32 (dt=w>>1), summing all 1024 keys from
// the block-wide LDS P buffer -> no cross-wave reduction needed.
__global__ __launch_bounds__(256, 2) void k_attn_pv(
    const unsigned short* __restrict__ Qb,
    const unsigned short* __restrict__ Kb,
    const unsigned short* __restrict__ Vtb,
    float* __restrict__ attn,
    unsigned short* __restrict__ ctx)
{
    __shared__ float wstat[4][32];
    // P bf16, one 32x256 chunk per wave, XOR-swizzled: byte ^= (row&7)<<4
    __shared__ __align__(16) unsigned short Pl[4][32 * 256];   // 64 KB
    const int blk = blockIdx.x;            // 4096 = 128 bh * 32 qtiles
    const int bh = blk >> 5;
    const int m0 = (blk & 31) * 32;
    const int tid = threadIdx.x;
    const int w = tid >> 6, l = tid & 63;
    const int lm = l & 15, q4 = l >> 4;
    const unsigned short* Qh = Qb  + (size_t)bh * SEQ * DKH;
    const unsigned short* Kh = Kb  + (size_t)bh * SEQ * DKH;
    const unsigned short* Vh = Vtb + (size_t)bh * DKH * SEQ;
    const int nw0 = w * 256;

    // ---- phase A: scores (Q pre-scaled by 0.125 in k_gemm<0>) ----
    short8 a[2][2];
#pragma unroll
    for (int mi = 0; mi < 2; ++mi)
#pragma unroll
        for (int ks = 0; ks < 2; ++ks)
            a[mi][ks] = *(const short8*)(Qh + (size_t)(m0 + mi * 16 + lm) * 64 + ks * 32 + q4 * 8);

    float4v acc[2][16];
#pragma unroll
    for (int cg = 0; cg < 16; ++cg) {
        const unsigned short* kp = Kh + (size_t)(nw0 + cg * 16 + lm) * 64 + q4 * 8;
        short8 b0 = *(const short8*)kp;
        short8 b1 = *(const short8*)(kp + 32);
#pragma unroll
        for (int mi = 0; mi < 2; ++mi) {
            float4v z = {0.f, 0.f, 0.f, 0.f};
            z = __builtin_amdgcn_mfma_f32_16x16x32_bf16(a[mi][0], b0, z, 0, 0, 0);
            acc[mi][cg] = __builtin_amdgcn_mfma_f32_16x16x32_bf16(a[mi][1], b1, z, 0, 0, 0);
        }
    }

    // ---- phase B: global row max ----
    float gM[2][4];
#pragma unroll
    for (int mi = 0; mi < 2; ++mi)
#pragma unroll
        for (int r = 0; r < 4; ++r) {
            float pm = -1e30f;
#pragma unroll
            for (int cg = 0; cg < 16; ++cg) pm = fmaxf(pm, acc[mi][cg][r]);
#pragma unroll
            for (int sh = 1; sh < 16; sh <<= 1) pm = fmaxf(pm, __shfl_xor(pm, sh));
            gM[mi][r] = pm;
        }
    if (lm == 0) {
#pragma unroll
        for (int mi = 0; mi < 2; ++mi)
#pragma unroll
            for (int r = 0; r < 4; ++r)
                wstat[w][mi * 16 + q4 * 4 + r] = gM[mi][r];
    }
    __syncthreads();
#pragma unroll
    for (int mi = 0; mi < 2; ++mi)
#pragma unroll
        for (int r = 0; r < 4; ++r) {
            int row = mi * 16 + q4 * 4 + r;
            gM[mi][r] = fmaxf(fmaxf(wstat[0][row], wstat[1][row]),
                              fmaxf(wstat[2][row], wstat[3][row]));
        }
    __syncthreads();

    // ---- exp + global row sum ----
    float gS[2][4];
#pragma unroll
    for (int mi = 0; mi < 2; ++mi)
#pragma unroll
        for (int r = 0; r < 4; ++r) {
            float ps = 0.f;
#pragma unroll
            for (int cg = 0; cg < 16; ++cg) {
                float e = __expf(acc[mi][cg][r] - gM[mi][r]);
                acc[mi][cg][r] = e;
                ps += e;
            }
#pragma unroll
            for (int sh = 1; sh < 16; sh <<= 1) ps += __shfl_xor(ps, sh);
            gS[mi][r] = ps;
        }
    if (lm == 0) {
#pragma unroll
        for (int mi = 0; mi < 2; ++mi)
#pragma unroll
            for (int r = 0; r < 4; ++r)
                wstat[w][mi * 16 + q4 * 4 + r] = gS[mi][r];
    }
    __syncthreads();
    float inv[2][4];
#pragma unroll
    for (int mi = 0; mi < 2; ++mi)
#pragma unroll
        for (int r = 0; r < 4; ++r) {
            int row = mi * 16 + q4 * 4 + r;
            inv[mi][r] = 1.f / (wstat[0][row] + wstat[1][row] + wstat[2][row] + wstat[3][row]);
        }

    // ---- phase C: write attn fp32 + pack bf16 P into swizzled LDS ----
    const size_t base = (size_t)bh * SEQ * SEQ;
    char* Pw = (char*)&Pl[w][0];
#pragma unroll
    for (int mi = 0; mi < 2; ++mi)
#pragma unroll
        for (int r = 0; r < 4; ++r) {
            const int row = mi * 16 + q4 * 4 + r;
            const int rx = (row & 7) << 4;
            const float iv = inv[mi][r];
            float* arow = attn + base + (size_t)(m0 + row) * SEQ + nw0;
#pragma unroll
            for (int cg = 0; cg < 16; ++cg) {
                float p = acc[mi][cg][r] * iv;
                arow[cg * 16 + lm] = p;
                *(unsigned short*)(Pw + row * 512 + (((cg * 16 + lm) * 2) ^ rx)) = f2bf(p);
            }
        }
    __syncthreads();

    // ---- phase D: PV. wave w -> rows rt*16..+16, d cols dt*32..+32, k = 0..1023
    const int rt = w & 1, dt = w >> 1;
    const int prow = rt * 16 + lm;                 // this lane's P row (A-frag)
    const int prx  = (prow & 7) << 4;
    float4v pv[2] = {};                            // ni = 0,1
    for (int kc = 0; kc < 32; ++kc) {              // k chunk of 32
        const int c    = kc >> 3;                  // source wave chunk (k/256)
        const int kloc = (kc & 7) * 32 + q4 * 8;   // k within chunk for this lane
        const char* Pc = (const char*)&Pl[c][0];
        short8 af = *(const short8*)(Pc + prow * 512 + ((kloc * 2) ^ prx));
        const int kg = kc * 32 + q4 * 8;           // global k for V fragment
#pragma unroll
        for (int ni = 0; ni < 2; ++ni) {
            short8 bfr = *(const short8*)(Vh + (size_t)(dt * 32 + ni * 16 + lm) * SEQ + kg);
            pv[ni] = __builtin_amdgcn_mfma_f32_16x16x32_bf16(af, bfr, pv[ni], 0, 0, 0);
        }
    }
    const int bb = bh >> 3, h = bh & 7;
#pragma unroll
    for (int ni = 0; ni < 2; ++ni)
#pragma unroll
        for (int r = 0; r < 4; ++r) {
            int s = m0 + rt * 16 + q4 * 4 + r;
            int d = dt * 32 + ni * 16 + lm;
            ctx[((size_t)(bb * SEQ + s)) * 512 + h * 64 + d] = f2bf(pv[ni][r]);
        }
}

// ---------------- launch ----------------
extern "C" void kernel_launch(void* const* d_in, const int* in_sizes, int n_in,
                              void* d_out, int out_size, void* d_ws, size_t ws_size,
                              hipStream_t stream) {
    const float* x  = (const float*)d_in[0];
    const float* Wq = (const float*)d_in[1];
    const float* bq = (const float*)d_in[2];
    const float* Wk = (const float*)d_in[3];
    const float* bk = (const float*)d_in[4];
    const float* Wv = (const float*)d_in[5];
    const float* bv = (const float*)d_in[6];
    const float* Wo = (const float*)d_in[7];
    const float* bo = (const float*)d_in[8];

    float* out  = (float*)d_out;
    float* attn = out + (size_t)M_TOT * D_MODELC;   // second output, 134,217,728 floats

    char* ws = (char*)d_ws;
    unsigned short* xb    = (unsigned short*)(ws);                       // 16 MB
    unsigned short* Qb    = (unsigned short*)(ws + (size_t)(16u << 20)); // 16 MB [bh][s][d], pre-scaled
    unsigned short* Kb    = (unsigned short*)(ws + (size_t)(32u << 20)); // 16 MB [bh][s][d]
    unsigned short* Vtb   = (unsigned short*)(ws + (size_t)(48u << 20)); // 16 MB [bh][d][s]
    unsigned short* ctxb  = (unsigned short*)(ws + (size_t)(64u << 20)); // 16 MB [b*s][h*64+d]
    unsigned short* Wqkvt = (unsigned short*)(ws + (size_t)(80u << 20)); // 1.5 MB [1536][512]
    unsigned short* Wot   = (unsigned short*)(ws + (size_t)(82u << 20)); // 0.5 MB [512][512]

    k_cvt_x<<<8192, 256, 0, stream>>>(x, xb);
    k_wt<<<1024, 256, 0, stream>>>(Wq, Wk, Wv, Wo, Wqkvt, Wot);
    k_gemm<0><<<dim3(12, 128), 256, 0, stream>>>(xb, Wqkvt, bq, bk, bv,
                                                 Qb, Kb, Vtb, nullptr);
    k_attn_pv<<<4096, 256, 0, stream>>>(Qb, Kb, Vtb, attn, ctxb);
    k_gemm<1><<<dim3(4, 128), 256, 0, stream>>>(ctxb, Wot, bo, nullptr, nullptr,
                                                nullptr, nullptr, nullptr, out);
}

// Round 2
// 839.399 us; speedup vs baseline: 1.1339x; 1.0230x over previous
//
#include <hip/hip_runtime.h>
#include <stdint.h>

#define D_MODELC 512
#define N_HEADSC 8
#define DKH 64
#define BATCH 16
#define SEQ 1024
#define M_TOT (BATCH*SEQ)    // 16384
#define NBH (BATCH*N_HEADSC) // 128

typedef __attribute__((ext_vector_type(8))) short short8;
typedef __attribute__((ext_vector_type(4))) float float4v;
typedef __attribute__((ext_vector_type(4))) unsigned short ushort4v;

__device__ inline unsigned short f2bf(float f) {
    unsigned u = __float_as_uint(f);
    u += 0x7FFFu + ((u >> 16) & 1u);   // RNE
    return (unsigned short)(u >> 16);
}

__device__ inline void gl2lds16(const void* g, void* l) {
    __builtin_amdgcn_global_load_lds(
        (__attribute__((address_space(1))) void*)g,
        (__attribute__((address_space(3))) void*)l, 16, 0, 0);
}

// ---------------- kernel 0a: x fp32 -> bf16 ----------------
__global__ void k_cvt_x(const float* __restrict__ x, unsigned short* __restrict__ xb) {
    int i = (blockIdx.x * 256 + threadIdx.x) * 4;   // 8192 blocks * 1024 = 8388608 exact
    float4v v = *(const float4v*)(x + i);
    ushort4v o;
    o.x = f2bf(v.x); o.y = f2bf(v.y); o.z = f2bf(v.z); o.w = f2bf(v.w);
    *(ushort4v*)(xb + i) = o;
}

// ---------------- kernel 0b: W (K,N) fp32 -> Wt[n][k] bf16, LDS tile transpose --------
__global__ void k_wt(const float* __restrict__ Wq, const float* __restrict__ Wk,
                     const float* __restrict__ Wv, const float* __restrict__ Wo,
                     unsigned short* __restrict__ Wqkvt, unsigned short* __restrict__ Wot) {
    __shared__ float tile[32][33];
    const int blk = blockIdx.x;            // 1024 = 4 mats * 16 * 16 tiles
    const int mat = blk >> 8;
    const int t2  = blk & 255;
    const int kt = (t2 >> 4) * 32;         // row of W (input dim k)
    const int nt = (t2 & 15) * 32;         // col of W (output dim n)
    const float* W = mat == 0 ? Wq : mat == 1 ? Wk : mat == 2 ? Wv : Wo;
    const int tid = threadIdx.x;
    const int cx = tid & 31, ry = tid >> 5;   // 8 rows per pass
#pragma unroll
    for (int p = 0; p < 4; ++p) {
        int kr = ry + p * 8;
        tile[kr][cx] = W[(size_t)(kt + kr) * 512 + nt + cx];
    }
    __syncthreads();
    unsigned short* DST = (mat < 3) ? (Wqkvt + (size_t)mat * 512 * 512) : Wot;
#pragma unroll
    for (int p = 0; p < 4; ++p) {
        int nr = ry + p * 8;
        DST[(size_t)(nt + nr) * 512 + kt + cx] = f2bf(tile[cx][nr]);
    }
}

// ---------------- GEMM: C = A(bf16 M x512) @ Bt^T + bias ----------------
// MODE 0: A=xb, Bt=Wqkv_t[1536][512]; epilogue scatters Q(scaled)/K/Vt bf16.
// MODE 1: A=ctx, Bt=Wo_t[512][512]; epilogue writes fp32 out + bo.
// 1D grid with bijective XCD swizzle: each XCD gets a contiguous chunk of
// m-panels so A-panels are fetched by one L2 only.
template<int MODE>
__global__ __launch_bounds__(256, 2) void k_gemm(
    const unsigned short* __restrict__ A,
    const unsigned short* __restrict__ Bt,
    const float* __restrict__ bias0,
    const float* __restrict__ bias1,
    const float* __restrict__ bias2,
    unsigned short* __restrict__ Qb,
    unsigned short* __restrict__ Kb,
    unsigned short* __restrict__ Vtb,
    float* __restrict__ Out)
{
    __shared__ __align__(16) unsigned short As[128 * 32];
    __shared__ __align__(16) unsigned short Bs[128 * 32];
    const int NT   = (MODE == 0) ? 12 : 4;           // n-tiles
    const int NWG  = (MODE == 0) ? 1536 : 512;       // total blocks, %8==0
    int fid = blockIdx.x;
    fid = (fid & 7) * (NWG >> 3) + (fid >> 3);       // XCD swizzle (bijective)
    const int n0 = (fid % NT) * 128;
    const int m0 = (fid / NT) * 128;
    const int tid = threadIdx.x;
    const int w = tid >> 6, l = tid & 63;
    const int lm = l & 15, q4 = l >> 4;
    const int wm = (w >> 1) * 64, wn = (w & 1) * 64;

    float4v acc[4][4] = {};

    for (int k0 = 0; k0 < 512; k0 += 32) {
#pragma unroll
        for (int r = 0; r < 2; ++r) {
            int e = tid * 8 + r * 2048;          // flat bf16 idx into 128x32 tile
            int row = e >> 5, col = e & 31;
            gl2lds16(A  + (size_t)(m0 + row) * 512 + k0 + col,
                     (char*)As + w * 1024 + r * 4096);
            gl2lds16(Bt + (size_t)(n0 + row) * 512 + k0 + col,
                     (char*)Bs + w * 1024 + r * 4096);
        }
        __syncthreads();
        short8 af[4], bfr[4];
#pragma unroll
        for (int mi = 0; mi < 4; ++mi)
            af[mi] = *(const short8*)(As + (wm + mi * 16 + lm) * 32 + q4 * 8);
#pragma unroll
        for (int ni = 0; ni < 4; ++ni)
            bfr[ni] = *(const short8*)(Bs + (wn + ni * 16 + lm) * 32 + q4 * 8);
#pragma unroll
        for (int mi = 0; mi < 4; ++mi)
#pragma unroll
            for (int ni = 0; ni < 4; ++ni)
                acc[mi][ni] = __builtin_amdgcn_mfma_f32_16x16x32_bf16(
                    af[mi], bfr[ni], acc[mi][ni], 0, 0, 0);
        __syncthreads();
    }

    if (MODE == 0) {
        const int which = (n0 + wn) >> 9;        // wave-uniform: 64-wide range never crosses 512
        if (which == 2) {
            // V: write transposed Vt[bh][d][s]; 4 r-values are consecutive s -> 8-B stores
#pragma unroll
            for (int mi = 0; mi < 4; ++mi)
#pragma unroll
                for (int ni = 0; ni < 4; ++ni) {
                    int nn = (n0 + wn + ni * 16 + lm) & 511;
                    int h = nn >> 6, d = nn & 63;
                    int s0 = m0 + wm + mi * 16 + q4 * 4;
                    int b = s0 >> 10, s = s0 & 1023;
                    float bv2 = bias2[nn];
                    ushort4v o;
                    o.x = f2bf(acc[mi][ni][0] + bv2);
                    o.y = f2bf(acc[mi][ni][1] + bv2);
                    o.z = f2bf(acc[mi][ni][2] + bv2);
                    o.w = f2bf(acc[mi][ni][3] + bv2);
                    *(ushort4v*)(Vtb + (((size_t)(b * N_HEADSC + h)) * DKH + d) * SEQ + s) = o;
                }
        } else {
#pragma unroll
            for (int mi = 0; mi < 4; ++mi)
#pragma unroll
                for (int ni = 0; ni < 4; ++ni) {
                    int nn = (n0 + wn + ni * 16 + lm) & 511;
                    int h = nn >> 6, d = nn & 63;
                    float bia = (which == 0) ? bias0[nn] : bias1[nn];
#pragma unroll
                    for (int r = 0; r < 4; ++r) {
                        int m = m0 + wm + mi * 16 + q4 * 4 + r;
                        int b = m >> 10, s = m & 1023;
                        size_t qkoff = (((size_t)(b * N_HEADSC + h)) * SEQ + s) * DKH + d;
                        float v = acc[mi][ni][r] + bia;
                        if (which == 0) v *= 0.125f;   // fold 1/sqrt(dk), exact pow2
                        ((which == 0) ? Qb : Kb)[qkoff] = f2bf(v);
                    }
                }
        }
    } else {
#pragma unroll
        for (int mi = 0; mi < 4; ++mi)
#pragma unroll
            for (int ni = 0; ni < 4; ++ni)
#pragma unroll
                for (int r = 0; r < 4; ++r) {
                    int m = m0 + wm + mi * 16 + q4 * 4 + r;
                    int n = n0 + wn + ni * 16 + lm;
                    Out[(size_t)m * 512 + n] = acc[mi][ni][r] + bias0[n];
                }
    }
}

// ---------------- kernel 2: scores + softmax + attn write + PV (fused) ----------------
// one block = 32 query rows of one (b,h). Phase A computes S^T = mfma(A=K, B=Q):
// lane owns query col lm, keys cg*16+q4*4+r on regs -> float4 attn stores,
// 8-B LDS P packs, in-lane row reductions (+2 shfl over q4 groups).
// Phase D (PV): wave w owns rows rt*16..+16 (rt=w&1), d cols dt*32..+32 (dt=w>>1).
__global__ __launch_bounds__(256, 2) void k_attn_pv(
    const unsigned short* __restrict__ Qb,
    const unsigned short* __restrict__ Kb,
    const unsigned short* __restrict__ Vtb,
    float* __restrict__ attn,
    unsigned short* __restrict__ ctx)
{
    __shared__ float wstat[4][32];
    // P bf16, one 32x256 chunk per wave, XOR-swizzled: byte ^= (row&7)<<4
    __shared__ __align__(16) unsigned short Pl[4][32 * 256];   // 64 KB
    int blk = blockIdx.x;
    blk = (blk & 7) * 512 + (blk >> 3);    // XCD swizzle: 16 heads stay on one XCD's L2
    const int bh = blk >> 5;
    const int m0 = (blk & 31) * 32;
    const int tid = threadIdx.x;
    const int w = tid >> 6, l = tid & 63;
    const int lm = l & 15, q4 = l >> 4;
    const unsigned short* Qh = Qb  + (size_t)bh * SEQ * DKH;
    const unsigned short* Kh = Kb  + (size_t)bh * SEQ * DKH;
    const unsigned short* Vh = Vtb + (size_t)bh * DKH * SEQ;
    const int nw0 = w * 256;

    // ---- phase A: S^T (Q pre-scaled by 0.125 in k_gemm<0>) ----
    short8 bq[2][2];                       // Q rows as B-fragments
#pragma unroll
    for (int mi = 0; mi < 2; ++mi)
#pragma unroll
        for (int ks = 0; ks < 2; ++ks)
            bq[mi][ks] = *(const short8*)(Qh + (size_t)(m0 + mi * 16 + lm) * 64 + ks * 32 + q4 * 8);

    float4v acc[2][16];                    // [query grp][key grp]; regs = consecutive keys
#pragma unroll
    for (int cg = 0; cg < 16; ++cg) {
        const unsigned short* kp = Kh + (size_t)(nw0 + cg * 16 + lm) * 64 + q4 * 8;
        short8 a0 = *(const short8*)kp;    // K rows as A-fragments
        short8 a1 = *(const short8*)(kp + 32);
#pragma unroll
        for (int mi = 0; mi < 2; ++mi) {
            float4v z = {0.f, 0.f, 0.f, 0.f};
            z = __builtin_amdgcn_mfma_f32_16x16x32_bf16(a0, bq[mi][0], z, 0, 0, 0);
            acc[mi][cg] = __builtin_amdgcn_mfma_f32_16x16x32_bf16(a1, bq[mi][1], z, 0, 0, 0);
        }
    }

    // ---- phase B: row max (in-lane over 64 vals + 2 shfl across q4 groups) ----
    float gM[2];
#pragma unroll
    for (int mi = 0; mi < 2; ++mi) {
        float pm = -1e30f;
#pragma unroll
        for (int cg = 0; cg < 16; ++cg)
#pragma unroll
            for (int r = 0; r < 4; ++r) pm = fmaxf(pm, acc[mi][cg][r]);
        pm = fmaxf(pm, __shfl_xor(pm, 16));
        pm = fmaxf(pm, __shfl_xor(pm, 32));
        gM[mi] = pm;
    }
    if (l < 16) {
#pragma unroll
        for (int mi = 0; mi < 2; ++mi) wstat[w][mi * 16 + lm] = gM[mi];
    }
    __syncthreads();
#pragma unroll
    for (int mi = 0; mi < 2; ++mi) {
        int row = mi * 16 + lm;
        gM[mi] = fmaxf(fmaxf(wstat[0][row], wstat[1][row]),
                       fmaxf(wstat[2][row], wstat[3][row]));
    }
    __syncthreads();

    // ---- exp + row sum ----
    float gS[2];
#pragma unroll
    for (int mi = 0; mi < 2; ++mi) {
        float ps = 0.f;
#pragma unroll
        for (int cg = 0; cg < 16; ++cg)
#pragma unroll
            for (int r = 0; r < 4; ++r) {
                float e = __expf(acc[mi][cg][r] - gM[mi]);
                acc[mi][cg][r] = e;
                ps += e;
            }
        ps += __shfl_xor(ps, 16);
        ps += __shfl_xor(ps, 32);
        gS[mi] = ps;
    }
    if (l < 16) {
#pragma unroll
        for (int mi = 0; mi < 2; ++mi) wstat[w][mi * 16 + lm] = gS[mi];
    }
    __syncthreads();
    float inv[2];
#pragma unroll
    for (int mi = 0; mi < 2; ++mi) {
        int row = mi * 16 + lm;
        inv[mi] = 1.f / (wstat[0][row] + wstat[1][row] + wstat[2][row] + wstat[3][row]);
    }

    // ---- phase C: float4 attn stores + 8-B swizzled LDS P pack ----
    const size_t base = (size_t)bh * SEQ * SEQ;
    char* Pw = (char*)&Pl[w][0];
#pragma unroll
    for (int mi = 0; mi < 2; ++mi) {
        const int row = mi * 16 + lm;          // query-local
        const int rx = (row & 7) << 4;
        const float iv = inv[mi];
        float* arow = attn + base + (size_t)(m0 + row) * SEQ + nw0 + q4 * 4;
#pragma unroll
        for (int cg = 0; cg < 16; ++cg) {
            float4v p = acc[mi][cg] * iv;
            *(float4v*)(arow + cg * 16) = p;
            ushort4v pb;
            pb.x = f2bf(p.x); pb.y = f2bf(p.y);
            pb.z = f2bf(p.z); pb.w = f2bf(p.w);
            *(ushort4v*)(Pw + row * 512 + ((cg * 32 + q4 * 8) ^ rx)) = pb;
        }
    }
    __syncthreads();

    // ---- phase D: PV. wave w -> rows rt*16..+16, d cols dt*32..+32, k = 0..1023
    const int rt = w & 1, dt = w >> 1;
    const int prow = rt * 16 + lm;                 // this lane's P row (A-frag)
    const int prx  = (prow & 7) << 4;
    float4v pv[2] = {};                            // ni = 0,1
    for (int kc = 0; kc < 32; ++kc) {              // k chunk of 32
        const int c    = kc >> 3;                  // source wave chunk (k/256)
        const int kloc = (kc & 7) * 32 + q4 * 8;   // k within chunk for this lane
        const char* Pc = (const char*)&Pl[c][0];
        short8 af = *(const short8*)(Pc + prow * 512 + ((kloc * 2) ^ prx));
        const int kg = kc * 32 + q4 * 8;           // global k for V fragment
#pragma unroll
        for (int ni = 0; ni < 2; ++ni) {
            short8 bfr = *(const short8*)(Vh + (size_t)(dt * 32 + ni * 16 + lm) * SEQ + kg);
            pv[ni] = __builtin_amdgcn_mfma_f32_16x16x32_bf16(af, bfr, pv[ni], 0, 0, 0);
        }
    }
    const int bb = bh >> 3, h = bh & 7;
#pragma unroll
    for (int ni = 0; ni < 2; ++ni)
#pragma unroll
        for (int r = 0; r < 4; ++r) {
            int s = m0 + rt * 16 + q4 * 4 + r;
            int d = dt * 32 + ni * 16 + lm;
            ctx[((size_t)(bb * SEQ + s)) * 512 + h * 64 + d] = f2bf(pv[ni][r]);
        }
}

// ---------------- launch ----------------
extern "C" void kernel_launch(void* const* d_in, const int* in_sizes, int n_in,
                              void* d_out, int out_size, void* d_ws, size_t ws_size,
                              hipStream_t stream) {
    const float* x  = (const float*)d_in[0];
    const float* Wq = (const float*)d_in[1];
    const float* bq = (const float*)d_in[2];
    const float* Wk = (const float*)d_in[3];
    const float* bk = (const float*)d_in[4];
    const float* Wv = (const float*)d_in[5];
    const float* bv = (const float*)d_in[6];
    const float* Wo = (const float*)d_in[7];
    const float* bo = (const float*)d_in[8];

    float* out  = (float*)d_out;
    float* attn = out + (size_t)M_TOT * D_MODELC;   // second output, 134,217,728 floats

    char* ws = (char*)d_ws;
    unsigned short* xb    = (unsigned short*)(ws);                       // 16 MB
    unsigned short* Qb    = (unsigned short*)(ws + (size_t)(16u << 20)); // 16 MB [bh][s][d], pre-scaled
    unsigned short* Kb    = (unsigned short*)(ws + (size_t)(32u << 20)); // 16 MB [bh][s][d]
    unsigned short* Vtb   = (unsigned short*)(ws + (size_t)(48u << 20)); // 16 MB [bh][d][s]
    unsigned short* ctxb  = (unsigned short*)(ws + (size_t)(64u << 20)); // 16 MB [b*s][h*64+d]
    unsigned short* Wqkvt = (unsigned short*)(ws + (size_t)(80u << 20)); // 1.5 MB [1536][512]
    unsigned short* Wot   = (unsigned short*)(ws + (size_t)(82u << 20)); // 0.5 MB [512][512]

    k_cvt_x<<<8192, 256, 0, stream>>>(x, xb);
    k_wt<<<1024, 256, 0, stream>>>(Wq, Wk, Wv, Wo, Wqkvt, Wot);
    k_gemm<0><<<1536, 256, 0, stream>>>(xb, Wqkvt, bq, bk, bv,
                                        Qb, Kb, Vtb, nullptr);
    k_attn_pv<<<4096, 256, 0, stream>>>(Qb, Kb, Vtb, attn, ctxb);
    k_gemm<1><<<512, 256, 0, stream>>>(ctxb, Wot, bo, nullptr, nullptr,
                                       nullptr, nullptr, nullptr, out);
}